// Round 1
// baseline (258.258 us; speedup 1.0000x reference)
//
#include <hip/hip_runtime.h>
#include <hip/hip_bf16.h>
#include <math.h>

// Problem constants (T=64, B=256, N=512)
#define TT 64
#define BB 256
#define NN 512
#define TB (TT*BB)            // 16384
#define TBN ((size_t)TB*NN)   // 8388608

// ---------------------------------------------------------------------------
// K1: gates — per b: row-means over N (→ spatial LIF scan over T) and
//     column means over T (→ temporal heaviside gate). One read of x.
// grid = B (256), block = 256
// ---------------------------------------------------------------------------
__global__ __launch_bounds__(256) void gates_kernel(
    const float* __restrict__ x, float* __restrict__ spatial, float* __restrict__ temporal) {
  int b = blockIdx.x;
  int tid = threadIdx.x;
  __shared__ float rm[TT];
  __shared__ float wsum[4];
  float col0 = 0.f, col1 = 0.f;
  for (int t = 0; t < TT; ++t) {
    const float* row = x + (size_t)(t * BB + b) * NN;
    float a = row[tid];
    float c = row[tid + 256];
    col0 += a; col1 += c;
    float v = a + c;
    #pragma unroll
    for (int off = 32; off > 0; off >>= 1) v += __shfl_down(v, off);
    if ((tid & 63) == 0) wsum[tid >> 6] = v;
    __syncthreads();
    if (tid == 0) rm[t] = (wsum[0] + wsum[1]) + (wsum[2] + wsum[3]);
    __syncthreads();
  }
  // temporal gate: heaviside(mean_t(x) - 1)
  float m0 = col0 * (1.0f / 64.0f);
  float m1 = col1 * (1.0f / 64.0f);
  temporal[b * NN + tid]       = (m0 - 1.0f >= 0.0f) ? 1.0f : 0.0f;
  temporal[b * NN + tid + 256] = (m1 - 1.0f >= 0.0f) ? 1.0f : 0.0f;
  // spatial: LIF scan over T on row-means (serial, tiny)
  if (tid == 0) {
    float v = 0.f;
    for (int t = 0; t < TT; ++t) {
      float m = rm[t] * (1.0f / 512.0f);
      v = v - v * 0.5f + m;                       // charge (tau=2, v_rst=0)
      float s = (v - 1.0f >= 0.0f) ? 1.0f : 0.0f; // fire
      spatial[t * BB + b] = s;
      v = (s != 0.0f) ? 0.0f : v;                 // hard reset
    }
  }
}

// ---------------------------------------------------------------------------
// K2: gated input + main LIF scan over T -> binary spikes (u8)
// grid = B (256), block = 128 (each thread owns 4 consecutive n)
// ---------------------------------------------------------------------------
__global__ __launch_bounds__(128) void spike_kernel(
    const float* __restrict__ x, const float* __restrict__ spatial,
    const float* __restrict__ temporal, unsigned char* __restrict__ spk) {
  int b = blockIdx.x;
  int tid = threadIdx.x;       // 0..127
  int n = tid * 4;
  float4 te = *(const float4*)(temporal + (size_t)b * NN + n);
  float v0 = 0.f, v1 = 0.f, v2 = 0.f, v3 = 0.f;
  for (int t = 0; t < TT; ++t) {
    float sp = spatial[t * BB + b];
    size_t base = (size_t)(t * BB + b) * NN + n;
    float4 xt = *(const float4*)(x + base);
    // s = (x*spatial)*(x*temporal); x' = x + s   (exact when gate==0)
    float a0 = xt.x + (xt.x * sp) * (xt.x * te.x);
    float a1 = xt.y + (xt.y * sp) * (xt.y * te.y);
    float a2 = xt.z + (xt.z * sp) * (xt.z * te.z);
    float a3 = xt.w + (xt.w * sp) * (xt.w * te.w);
    v0 = v0 - v0 * 0.5f + a0;
    v1 = v1 - v1 * 0.5f + a1;
    v2 = v2 - v2 * 0.5f + a2;
    v3 = v3 - v3 * 0.5f + a3;
    unsigned char s0 = (v0 - 1.0f >= 0.0f) ? 1 : 0;
    unsigned char s1 = (v1 - 1.0f >= 0.0f) ? 1 : 0;
    unsigned char s2 = (v2 - 1.0f >= 0.0f) ? 1 : 0;
    unsigned char s3 = (v3 - 1.0f >= 0.0f) ? 1 : 0;
    if (s0) v0 = 0.f;
    if (s1) v1 = 0.f;
    if (s2) v2 = 0.f;
    if (s3) v3 = 0.f;
    *(uchar4*)(spk + base) = make_uchar4(s0, s1, s2, s3);
  }
}

// ---------------------------------------------------------------------------
// K3: fp32 SIMT GEMM  y[r][m] = sum_k spk[r][k] * W[m][k]
// tile 128x128, KC=16, 256 threads, 8x8 per thread. Writes y into d_out.
// grid = (4, 128)
// ---------------------------------------------------------------------------
#define KC 16
__global__ __launch_bounds__(256) void gemm_kernel(
    const unsigned char* __restrict__ A, const float* __restrict__ W, float* __restrict__ C) {
  __shared__ float As[KC][128];   // [k][row]
  __shared__ float Bs[KC][144];   // [k][col], staggered: idx = m + 4*(m>>5)
  int tid = threadIdx.x;
  int col0 = blockIdx.x * 128;
  int row0 = blockIdx.y * 128;
  int tx = tid & 15, ty = tid >> 4;
  float acc[8][8] = {};
  for (int kc = 0; kc < NN; kc += KC) {
    // stage A: 128 rows x 16 u8 -> float (transposed)
    {
      int r = tid >> 1, half = (tid & 1) * 8;
      const unsigned char* p = A + (size_t)(row0 + r) * NN + kc + half;
      uint2 u = *(const uint2*)p;
      #pragma unroll
      for (int j = 0; j < 8; ++j) {
        unsigned byte = ((j < 4) ? (u.x >> (8 * j)) : (u.y >> (8 * (j - 4)))) & 0xFFu;
        As[half + j][r] = (float)byte;
      }
    }
    // stage B: W[col0+m][kc..kc+15] (transposed, staggered cols)
    {
      int m = tid >> 1, koff = (tid & 1) * 8;
      const float* p = W + (size_t)(col0 + m) * NN + kc + koff;
      float4 w0 = *(const float4*)p;
      float4 w1 = *(const float4*)(p + 4);
      int mi = m + 4 * (m >> 5);
      Bs[koff + 0][mi] = w0.x; Bs[koff + 1][mi] = w0.y;
      Bs[koff + 2][mi] = w0.z; Bs[koff + 3][mi] = w0.w;
      Bs[koff + 4][mi] = w1.x; Bs[koff + 5][mi] = w1.y;
      Bs[koff + 6][mi] = w1.z; Bs[koff + 7][mi] = w1.w;
    }
    __syncthreads();
    #pragma unroll
    for (int k = 0; k < KC; ++k) {
      float a[8], bb[8];
      #pragma unroll
      for (int i = 0; i < 8; ++i) a[i] = As[k][ty * 8 + i];
      #pragma unroll
      for (int j = 0; j < 8; ++j) {
        int m = tx * 8 + j;
        bb[j] = Bs[k][m + 4 * (m >> 5)];
      }
      #pragma unroll
      for (int i = 0; i < 8; ++i)
        #pragma unroll
        for (int j = 0; j < 8; ++j) acc[i][j] += a[i] * bb[j];
    }
    __syncthreads();
  }
  #pragma unroll
  for (int i = 0; i < 8; ++i) {
    float* cp = C + (size_t)(row0 + ty * 8 + i) * NN + col0 + tx * 8;
    float4 o0 = {acc[i][0], acc[i][1], acc[i][2], acc[i][3]};
    float4 o1 = {acc[i][4], acc[i][5], acc[i][6], acc[i][7]};
    *(float4*)cp = o0;
    *(float4*)(cp + 4) = o1;
  }
}

// ---------------------------------------------------------------------------
// K4: BN stats partial sums (deterministic two-stage, no atomics)
// grid = 128 row-chunks, block = 256 (2 channels each)
// ---------------------------------------------------------------------------
__global__ __launch_bounds__(256) void bnstats_kernel(
    const float* __restrict__ y, float* __restrict__ pS, float* __restrict__ pQ) {
  int c = blockIdx.x, tid = threadIdx.x;
  float s0 = 0.f, q0 = 0.f, s1 = 0.f, q1 = 0.f;
  for (int r = 0; r < 128; ++r) {
    const float* row = y + (size_t)(c * 128 + r) * NN;
    float a = row[tid];
    float b2 = row[tid + 256];
    s0 += a; q0 += a * a;
    s1 += b2; q1 += b2 * b2;
  }
  pS[c * NN + tid] = s0; pS[c * NN + tid + 256] = s1;
  pQ[c * NN + tid] = q0; pQ[c * NN + tid + 256] = q1;
}

// K5: finalize per-channel mean / inv-std
__global__ __launch_bounds__(512) void bnfinal_kernel(
    const float* __restrict__ pS, const float* __restrict__ pQ,
    float* __restrict__ mu, float* __restrict__ inv) {
  int m = threadIdx.x;
  float s = 0.f, q = 0.f;
  for (int c = 0; c < 128; ++c) { s += pS[c * NN + m]; q += pQ[c * NN + m]; }
  float mean = s * (1.0f / 16384.0f);
  float var  = q * (1.0f / 16384.0f) - mean * mean;
  mu[m] = mean;
  inv[m] = 1.0f / sqrtf(var + 1e-5f);
}

// ---------------------------------------------------------------------------
// K6: BN normalize + final LIF scan; in-place on d_out (reads y, writes spikes)
// grid = 512, block = 256 (thread per (b, m))
// ---------------------------------------------------------------------------
__global__ __launch_bounds__(256) void final_kernel(
    float* __restrict__ y, const float* __restrict__ mu, const float* __restrict__ inv,
    const float* __restrict__ gamma, const float* __restrict__ beta) {
  int g = blockIdx.x * 256 + threadIdx.x;   // 0..131071
  int b = g >> 9, m = g & 511;
  float MU = mu[m], IV = inv[m], G = gamma[m], BE = beta[m];
  float v = 0.f;
  for (int t = 0; t < TT; ++t) {
    size_t idx = (size_t)(t * BB + b) * NN + m;
    float xv = y[idx];
    float xb = ((xv - MU) * IV) * G + BE;
    v = v - v * 0.5f + xb;
    float s = (v - 1.0f >= 0.0f) ? 1.0f : 0.0f;
    y[idx] = s;
    v = (s != 0.0f) ? 0.0f : v;
  }
}

// ---------------------------------------------------------------------------
extern "C" void kernel_launch(void* const* d_in, const int* in_sizes, int n_in,
                              void* d_out, int out_size, void* d_ws, size_t ws_size,
                              hipStream_t stream) {
  const float* x     = (const float*)d_in[0];   // [T,B,N]
  const float* W     = (const float*)d_in[1];   // [N,N]
  const float* gamma = (const float*)d_in[2];   // [N]
  const float* beta  = (const float*)d_in[3];   // [N]
  float* out = (float*)d_out;                   // [T,B,N] fp32

  // workspace layout
  char* ws = (char*)d_ws;
  unsigned char* spikes = (unsigned char*)ws;                 //  8,388,608 B
  float* spatial  = (float*)(ws + 8388608);                   //     65,536 B
  float* temporal = (float*)(ws + 8454144);                   //    524,288 B
  float* partS    = (float*)(ws + 8978432);                   //    262,144 B
  float* partQ    = (float*)(ws + 9240576);                   //    262,144 B
  float* bn_mu    = (float*)(ws + 9502720);                   //      2,048 B
  float* bn_inv   = (float*)(ws + 9504768);                   //      2,048 B

  gates_kernel<<<dim3(BB), dim3(256), 0, stream>>>(x, spatial, temporal);
  spike_kernel<<<dim3(BB), dim3(128), 0, stream>>>(x, spatial, temporal, spikes);
  gemm_kernel<<<dim3(4, 128), dim3(256), 0, stream>>>(spikes, W, out);
  bnstats_kernel<<<dim3(128), dim3(256), 0, stream>>>(out, partS, partQ);
  bnfinal_kernel<<<dim3(1), dim3(512), 0, stream>>>(partS, partQ, bn_mu, bn_inv);
  final_kernel<<<dim3(512), dim3(256), 0, stream>>>(out, bn_mu, bn_inv, gamma, beta);
}

// Round 2
// 210.234 us; speedup vs baseline: 1.2284x; 1.2284x over previous
//
#include <hip/hip_runtime.h>
#include <hip/hip_bf16.h>
#include <math.h>

// Problem constants (T=64, B=256, N=512)
#define TT 64
#define BB 256
#define NN 512

typedef int i32x4  __attribute__((ext_vector_type(4)));
typedef int i32x16 __attribute__((ext_vector_type(16)));

// ---------------------------------------------------------------------------
// K0: W -> 4 signed-i8 digit planes of round(W * 2^30).  |W|<=0.0766 so
// W_int fits 27 bits; digit3 in [-9,9]. Reconstruction is exact:
// W_int = d0 + (d1<<8) + (d2<<16) + (d3<<24).
// ---------------------------------------------------------------------------
__global__ __launch_bounds__(256) void wprep_kernel(
    const float* __restrict__ W, signed char* __restrict__ wd) {
  int i = blockIdx.x * 256 + threadIdx.x;       // grid 1024 -> 262144 weights
  float v = W[i];
  int q = __float2int_rn(v * 1073741824.0f);    // * 2^30, round-nearest
  int d0 = ((q + 128) & 255) - 128; q = (q - d0) >> 8;
  int d1 = ((q + 128) & 255) - 128; q = (q - d1) >> 8;
  int d2 = ((q + 128) & 255) - 128; q = (q - d2) >> 8;
  wd[i]          = (signed char)d0;
  wd[262144 + i] = (signed char)d1;
  wd[524288 + i] = (signed char)d2;
  wd[786432 + i] = (signed char)q;              // |q| <= 9
}

// ---------------------------------------------------------------------------
// K1: gates. One block per b (512 threads = 512 channels).
// Per t: coalesced 2KB read; per-wave shfl row-reduce (NO syncthreads in loop).
// Emits spatial LIF spikes [T,B] and temporal heaviside gate [B,N].
// ---------------------------------------------------------------------------
__global__ __launch_bounds__(512) void gates_kernel(
    const float* __restrict__ x, float* __restrict__ spatial,
    float* __restrict__ temporal) {
  int b = blockIdx.x, tid = threadIdx.x;
  int l = tid & 63, w = tid >> 6;               // 8 waves
  __shared__ float rowpart[TT][8];
  __shared__ float rm[TT];
  float colsum = 0.f;
  const float* xb = x + (size_t)b * NN;
  for (int t = 0; t < TT; ++t) {
    float v = xb[(size_t)t * (BB * NN) + tid];
    colsum += v;
    float r = v;
    #pragma unroll
    for (int off = 32; off; off >>= 1) r += __shfl_xor(r, off);
    if (l == 0) rowpart[t][w] = r;
  }
  __syncthreads();
  if (tid < TT) {
    float s = 0.f;
    #pragma unroll
    for (int k = 0; k < 8; ++k) s += rowpart[tid][k];
    rm[tid] = s;
  }
  __syncthreads();
  if (tid == 0) {                               // spatial LIF scan (tiny)
    float v = 0.f;
    for (int t = 0; t < TT; ++t) {
      float m = rm[t] * (1.0f / 512.0f);
      v = v - v * 0.5f + m;                     // charge (exact halving)
      float s = (v >= 1.0f) ? 1.0f : 0.0f;      // fire (== v-1>=0)
      spatial[t * BB + b] = s;
      if (s != 0.f) v = 0.f;                    // hard reset
    }
  }
  float m = colsum * (1.0f / 64.0f);
  temporal[(size_t)b * NN + tid] = (m >= 1.0f) ? 1.0f : 0.0f;
}

// ---------------------------------------------------------------------------
// K2: gated input + main LIF scan -> binary spikes (u8).
// One block per b, 256 threads x float2 (8B/lane loads).
// s = (x*sp)*(x*te) is exactly 0 whenever either gate is 0 (a.s. the case),
// so x+s == x bit-exactly and GEMM inputs match the reference.
// ---------------------------------------------------------------------------
__global__ __launch_bounds__(256) void spike_kernel(
    const float* __restrict__ x, const float* __restrict__ spatial,
    const float* __restrict__ temporal, unsigned char* __restrict__ spk) {
  int b = blockIdx.x, tid = threadIdx.x;
  int n = tid * 2;
  float2 te = *(const float2*)(temporal + (size_t)b * NN + n);
  const float* xb = x + (size_t)b * NN + n;
  unsigned char* sb = spk + (size_t)b * NN + n;
  float v0 = 0.f, v1 = 0.f;
  for (int t = 0; t < TT; ++t) {
    float sp = spatial[t * BB + b];
    float2 xt = *(const float2*)(xb + (size_t)t * (BB * NN));
    float a0 = xt.x + (xt.x * sp) * (xt.x * te.x);
    float a1 = xt.y + (xt.y * sp) * (xt.y * te.y);
    v0 = v0 - v0 * 0.5f + a0;
    v1 = v1 - v1 * 0.5f + a1;
    unsigned char s0 = (v0 >= 1.0f) ? 1 : 0;
    unsigned char s1 = (v1 >= 1.0f) ? 1 : 0;
    if (s0) v0 = 0.f;
    if (s1) v1 = 0.f;
    *(uchar2*)(sb + (size_t)t * (BB * NN)) = make_uchar2(s0, s1);
  }
}

// ---------------------------------------------------------------------------
// K3: i8 MFMA GEMM. y[r][m] = 2^-30 * sum_d 2^(8d) * sum_k spk[r][k]*Wd[d][m][k]
// Block = 4 waves (2x2) -> 128 rows x 64 cols. Wave = 64 rows x 32 cols.
// Per kstep(32): 2 A-frag + 4 B-frag loads (16B contiguous/lane), 8 MFMA.
// No LDS, no barriers — register pipelining only.
// Fragment layouts (32x32x32 i8): A: row=l&31, k=(l>>5)*16+j (j=byte idx);
// B: col=l&31, k likewise; C/D: col=l&31, row=(j&3)+8*(j>>2)+4*(l>>5).
// ---------------------------------------------------------------------------
__global__ __launch_bounds__(256) void gemm_kernel(
    const unsigned char* __restrict__ A, const signed char* __restrict__ Wd,
    float* __restrict__ C) {
  int tid = threadIdx.x;
  int l = tid & 63, w = tid >> 6;
  int wr = w >> 1, wc = w & 1;
  int row0 = blockIdx.x * 128 + wr * 64;
  int col0 = blockIdx.y * 64 + wc * 32;
  int lr = l & 31, lk = (l >> 5) * 16;
  const unsigned char* pa = A + (size_t)(row0 + lr) * NN + lk;
  const signed char*   pb = Wd + (size_t)(col0 + lr) * NN + lk;

  i32x16 acc[2][4];
  #pragma unroll
  for (int i = 0; i < 2; ++i)
    #pragma unroll
    for (int d = 0; d < 4; ++d)
      #pragma unroll
      for (int j = 0; j < 16; ++j) acc[i][d][j] = 0;

  for (int kk = 0; kk < NN; kk += 32) {
    i32x4 a0 = *(const i32x4*)(pa + kk);
    i32x4 a1 = *(const i32x4*)(pa + kk + 32 * NN);
    #pragma unroll
    for (int d = 0; d < 4; ++d) {
      i32x4 b = *(const i32x4*)(pb + kk + d * 262144);
      acc[0][d] = __builtin_amdgcn_mfma_i32_32x32x32_i8(a0, b, acc[0][d], 0, 0, 0);
      acc[1][d] = __builtin_amdgcn_mfma_i32_32x32x32_i8(a1, b, acc[1][d], 0, 0, 0);
    }
  }
  // exact digit combine: |S3|<=512*9 -> t2<2^21, t1<2^30, total in i64
  #pragma unroll
  for (int i = 0; i < 2; ++i) {
    #pragma unroll
    for (int j = 0; j < 16; ++j) {
      int t2 = acc[i][2][j] + (acc[i][3][j] << 8);
      int t1 = acc[i][1][j] + (t2 << 8);
      long long tt = ((long long)t1 << 8) + (long long)acc[i][0][j];
      float y = (float)tt * 0x1p-30f;
      int row = row0 + i * 32 + (j & 3) + 8 * (j >> 2) + 4 * (l >> 5);
      C[(size_t)row * NN + col0 + lr] = y;
    }
  }
}

// ---------------------------------------------------------------------------
// K4: BN stats stage A — 512 chunks x 32 rows, partials layout [ch][chunk]
// ---------------------------------------------------------------------------
__global__ __launch_bounds__(256) void bnstatsA_kernel(
    const float* __restrict__ y, float* __restrict__ pS, float* __restrict__ pQ) {
  int c = blockIdx.x, tid = threadIdx.x;        // rows [c*32, c*32+32)
  const float* base = y + (size_t)c * 32 * NN;
  float s0 = 0.f, q0 = 0.f, s1 = 0.f, q1 = 0.f;
  for (int r = 0; r < 32; ++r) {
    float a = base[r * NN + tid];
    float b = base[r * NN + tid + 256];
    s0 += a; q0 += a * a;
    s1 += b; q1 += b * b;
  }
  pS[(size_t)tid * 512 + c] = s0; pS[(size_t)(tid + 256) * 512 + c] = s1;
  pQ[(size_t)tid * 512 + c] = q0; pQ[(size_t)(tid + 256) * 512 + c] = q1;
}

// K5: BN stats stage B — 8 blocks x 512 thr, 8 lanes per channel, shfl reduce
__global__ __launch_bounds__(512) void bnstatsB_kernel(
    const float* __restrict__ pS, const float* __restrict__ pQ,
    float* __restrict__ mu, float* __restrict__ inv) {
  int tid = threadIdx.x, h = blockIdx.x;
  int ch = h * 64 + (tid >> 3), p = tid & 7;
  const float* ps = pS + (size_t)ch * 512 + p * 64;
  const float* pq = pQ + (size_t)ch * 512 + p * 64;
  float s = 0.f, q = 0.f;
  for (int i = 0; i < 64; ++i) { s += ps[i]; q += pq[i]; }
  #pragma unroll
  for (int off = 1; off < 8; off <<= 1) {
    s += __shfl_xor(s, off);
    q += __shfl_xor(q, off);
  }
  if (p == 0) {
    float mean = s * (1.0f / 16384.0f);
    float var  = q * (1.0f / 16384.0f) - mean * mean;
    mu[ch] = mean;
    inv[ch] = 1.0f / sqrtf(var + 1e-5f);
  }
}

// ---------------------------------------------------------------------------
// K6: BN normalize + final LIF scan; in-place on d_out
// ---------------------------------------------------------------------------
__global__ __launch_bounds__(256) void final_kernel(
    float* __restrict__ y, const float* __restrict__ mu, const float* __restrict__ inv,
    const float* __restrict__ gamma, const float* __restrict__ beta) {
  int g = blockIdx.x * 256 + threadIdx.x;       // 0..131071
  int b = g >> 9, m = g & 511;
  float MU = mu[m], IV = inv[m], G = gamma[m], BE = beta[m];
  float v = 0.f;
  for (int t = 0; t < TT; ++t) {
    size_t idx = (size_t)(t * BB + b) * NN + m;
    float xv = y[idx];
    float xb = ((xv - MU) * IV) * G + BE;
    v = v - v * 0.5f + xb;
    float s = (v >= 1.0f) ? 1.0f : 0.0f;
    y[idx] = s;
    if (s != 0.f) v = 0.f;
  }
}

// ---------------------------------------------------------------------------
extern "C" void kernel_launch(void* const* d_in, const int* in_sizes, int n_in,
                              void* d_out, int out_size, void* d_ws, size_t ws_size,
                              hipStream_t stream) {
  const float* x     = (const float*)d_in[0];   // [T,B,N]
  const float* W     = (const float*)d_in[1];   // [N,N]
  const float* gamma = (const float*)d_in[2];   // [N]
  const float* beta  = (const float*)d_in[3];   // [N]
  float* out = (float*)d_out;                   // [T,B,N] fp32

  // workspace layout (~11.6 MB)
  char* ws = (char*)d_ws;
  signed char* wd       = (signed char*)ws;                    // 1,048,576
  unsigned char* spikes = (unsigned char*)(ws + 1048576);      // 8,388,608
  float* spatial  = (float*)(ws + 9437184);                    //    65,536
  float* temporal = (float*)(ws + 9502720);                    //   524,288
  float* partS    = (float*)(ws + 10027008);                   // 1,048,576
  float* partQ    = (float*)(ws + 11075584);                   // 1,048,576
  float* bn_mu    = (float*)(ws + 12124160);                   //     2,048
  float* bn_inv   = (float*)(ws + 12126208);                   //     2,048

  wprep_kernel<<<dim3(1024), dim3(256), 0, stream>>>(W, wd);
  gates_kernel<<<dim3(BB), dim3(512), 0, stream>>>(x, spatial, temporal);
  spike_kernel<<<dim3(BB), dim3(256), 0, stream>>>(x, spatial, temporal, spikes);
  gemm_kernel<<<dim3(128, 8), dim3(256), 0, stream>>>(spikes, wd, out);
  bnstatsA_kernel<<<dim3(512), dim3(256), 0, stream>>>(out, partS, partQ);
  bnstatsB_kernel<<<dim3(8), dim3(512), 0, stream>>>(partS, partQ, bn_mu, bn_inv);
  final_kernel<<<dim3(512), dim3(256), 0, stream>>>(out, bn_mu, bn_inv, gamma, beta);
}

// Round 4
// 152.547 us; speedup vs baseline: 1.6930x; 1.3782x over previous
//
#include <hip/hip_runtime.h>
#include <hip/hip_bf16.h>
#include <math.h>

// Problem constants (T=64, B=256, N=512)
#define TT 64
#define BB 256
#define NN 512

typedef int i32x4  __attribute__((ext_vector_type(4)));
typedef int i32x16 __attribute__((ext_vector_type(16)));

// global -> LDS direct DMA, 16B per lane. LDS dest must be wave-uniform base
// (HW adds lane*16); global src is per-lane.
__device__ __forceinline__ void gload16(const void* g, void* l) {
  __builtin_amdgcn_global_load_lds(
      (const __attribute__((address_space(1))) unsigned int*)g,
      (__attribute__((address_space(3))) unsigned int*)l, 16, 0, 0);
}

// ---------------------------------------------------------------------------
// K0: W -> 4 signed-i8 digit planes of round(W * 2^30). Exact reconstruction:
// W_int = d0 + (d1<<8) + (d2<<16) + (d3<<24); |W|<=0.0766 -> fits 27 bits.
// ---------------------------------------------------------------------------
__global__ __launch_bounds__(256) void wprep_kernel(
    const float* __restrict__ W, signed char* __restrict__ wd) {
  int i = blockIdx.x * 256 + threadIdx.x;
  float v = W[i];
  int q = __float2int_rn(v * 1073741824.0f);
  int d0 = ((q + 128) & 255) - 128; q = (q - d0) >> 8;
  int d1 = ((q + 128) & 255) - 128; q = (q - d1) >> 8;
  int d2 = ((q + 128) & 255) - 128; q = (q - d2) >> 8;
  wd[i]          = (signed char)d0;
  wd[262144 + i] = (signed char)d1;
  wd[524288 + i] = (signed char)d2;
  wd[786432 + i] = (signed char)q;   // |q| <= 9
}

// ---------------------------------------------------------------------------
// K1: fused front-end. One block per b. Stage x[:,b,:] (128KB) into LDS once
// via global_load_lds, then row-means -> spatial LIF, col-means -> temporal
// gate, then the main gated LIF scan -> u8 spikes. x read from HBM once.
// ---------------------------------------------------------------------------
__global__ __launch_bounds__(512) void frontend_kernel(
    const float* __restrict__ x, unsigned char* __restrict__ spk) {
  extern __shared__ float xs[];          // [64][512] = 128 KB
  __shared__ float rms[TT];
  __shared__ float sp[TT];
  int b = blockIdx.x, tid = threadIdx.x;
  int l = tid & 63, w = tid >> 6;        // 8 waves
  #pragma unroll
  for (int p = 0; p < 16; ++p) {
    int f = p * 512 + tid;
    int t = f >> 7, c4 = f & 127;        // row t, float4 col c4
    gload16(x + (size_t)t * (BB * NN) + (size_t)b * NN + c4 * 4,
            (char*)xs + p * 8192 + w * 1024);
  }
  __syncthreads();                       // drains vmcnt(0) before barrier
  #pragma unroll
  for (int j = 0; j < 8; ++j) {
    int t = w * 8 + j;
    float s = 0.f;
    #pragma unroll
    for (int q = 0; q < 8; ++q) s += xs[t * 512 + q * 64 + l];
    #pragma unroll
    for (int off = 32; off; off >>= 1) s += __shfl_xor(s, off);
    if (l == 0) rms[t] = s;
  }
  float cs = 0.f;
  for (int t = 0; t < TT; ++t) cs += xs[t * 512 + tid];
  __syncthreads();
  if (tid == 0) {                        // spatial LIF scan (tiny serial)
    float v = 0.f;
    for (int t = 0; t < TT; ++t) {
      float m = rms[t] * (1.0f / 512.0f);
      v = v - v * 0.5f + m;
      float s = (v >= 1.0f) ? 1.0f : 0.0f;
      sp[t] = s;
      if (s != 0.f) v = 0.f;
    }
  }
  __syncthreads();
  float te = (cs * (1.0f / 64.0f) >= 1.0f) ? 1.0f : 0.0f;
  float v = 0.f;
  unsigned char* sb = spk + (size_t)b * NN + tid;
  for (int t = 0; t < TT; ++t) {
    float xv = xs[t * 512 + tid];
    float a = xv + (xv * sp[t]) * (xv * te);  // ==xv exactly when a gate is 0
    v = v - v * 0.5f + a;
    unsigned char s = (v >= 1.0f) ? 1 : 0;
    sb[(size_t)t * (BB * NN)] = s;
    if (s) v = 0.f;
  }
}

// ---------------------------------------------------------------------------
// K2: i8 MFMA GEMM with LDS double-buffer 2-phase pipeline.
// Block: 4 waves (2x2) -> 128 rows x 64 cols; BK=64 (2 k-steps of 32).
// Staged with pre-swizzled global addresses so LDS is fragment-ordered:
// chunk*1024 + lane*16 -> every ds_read_b128 is lane-linear, conflict-free.
// Epilogue: exact digit combine + C write + BN partial stats.
// ---------------------------------------------------------------------------
__global__ __launch_bounds__(256) void gemm_kernel(
    const unsigned char* __restrict__ A, const signed char* __restrict__ Wd,
    float* __restrict__ C, float* __restrict__ pS, float* __restrict__ pQ) {
  __shared__ unsigned char sm[2][24576];
  int tid = threadIdx.x;
  int l = tid & 63, w = tid >> 6;
  int wr = w >> 1, wc = w & 1;
  int bx = blockIdx.x, by = blockIdx.y;
  int row0 = bx * 128, col0 = by * 64;
  int lr = l & 31, lh = l >> 5;

  i32x16 acc[2][4];
  #pragma unroll
  for (int f = 0; f < 2; ++f)
    #pragma unroll
    for (int d = 0; d < 4; ++d)
      #pragma unroll
      for (int j = 0; j < 16; ++j) acc[f][d][j] = 0;

  auto STAGE = [&](unsigned char* lbase, int kk) {
    #pragma unroll
    for (int j = 0; j < 2; ++j) {        // A chunks: c = wr_*4 + ff*2 + ss
      int c = j * 4 + w;
      int wr_ = c >> 2, ff = (c >> 1) & 1, ss = c & 1;
      gload16(A + (size_t)(row0 + wr_ * 64 + ff * 32 + lr) * NN + kk + ss * 32 + lh * 16,
              lbase + j * 4096 + w * 1024);
    }
    #pragma unroll
    for (int j = 0; j < 4; ++j) {        // B chunks: c = wc_*8 + dd*2 + ss
      int c = j * 4 + w;
      int wc_ = c >> 3, dd = (c >> 1) & 3, ss = c & 1;
      gload16(Wd + (size_t)dd * (NN * NN) + (size_t)(col0 + wc_ * 32 + lr) * NN + kk + ss * 32 + lh * 16,
              lbase + 8192 + j * 4096 + w * 1024);
    }
  };

  STAGE(sm[0], 0);
  __syncthreads();
  int cur = 0;
  for (int t = 0; t < 8; ++t) {
    if (t < 7) STAGE(sm[cur ^ 1], (t + 1) * 64);   // prefetch next tile
    const unsigned char* bp = sm[cur];
    i32x4 a[2][2], bfr[4][2];
    #pragma unroll
    for (int f = 0; f < 2; ++f)
      #pragma unroll
      for (int s = 0; s < 2; ++s)
        a[f][s] = *(const i32x4*)(bp + ((wr * 2 + f) * 2 + s) * 1024 + l * 16);
    #pragma unroll
    for (int d = 0; d < 4; ++d)
      #pragma unroll
      for (int s = 0; s < 2; ++s)
        bfr[d][s] = *(const i32x4*)(bp + 8192 + ((wc * 4 + d) * 2 + s) * 1024 + l * 16);
    #pragma unroll
    for (int s = 0; s < 2; ++s)
      #pragma unroll
      for (int f = 0; f < 2; ++f)
        #pragma unroll
        for (int d = 0; d < 4; ++d)
          acc[f][d] = __builtin_amdgcn_mfma_i32_32x32x32_i8(a[f][s], bfr[d][s], acc[f][d], 0, 0, 0);
    __syncthreads();   // drains vmcnt (prefetch landed) + LDS reuse safety
    cur ^= 1;
  }

  // epilogue: exact digit combine, C write, BN partials.
  // NOTE: lanes lh=0 and lh=1 share the same column but cover different rows
  // -> must combine across the lane^32 pair before writing partials (R3 bug).
  int col = col0 + wc * 32 + lr;
  float sy = 0.f, sq = 0.f;
  #pragma unroll
  for (int f = 0; f < 2; ++f) {
    #pragma unroll
    for (int j = 0; j < 16; ++j) {
      int t2 = acc[f][2][j] + (acc[f][3][j] << 8);
      int t1 = acc[f][1][j] + (t2 << 8);
      long long tt = ((long long)t1 << 8) + (long long)acc[f][0][j];
      float y = (float)tt * 0x1p-30f;
      int row = row0 + wr * 64 + f * 32 + (j & 3) + 8 * (j >> 2) + 4 * lh;
      C[(size_t)row * NN + col] = y;
      sy += y; sq += y * y;
    }
  }
  sy += __shfl_xor(sy, 32);              // combine lh=0 + lh=1 halves
  sq += __shfl_xor(sq, 32);
  if (lh == 0) {
    pS[(size_t)col * 256 + bx * 2 + wr] = sy;
    pQ[(size_t)col * 256 + bx * 2 + wr] = sq;
  }
}

// ---------------------------------------------------------------------------
// K3: reduce 256 BN partials per channel -> mu, inv-std
// ---------------------------------------------------------------------------
__global__ __launch_bounds__(512) void bnstatsB_kernel(
    const float* __restrict__ pS, const float* __restrict__ pQ,
    float* __restrict__ mu, float* __restrict__ inv) {
  int tid = threadIdx.x;
  int ch = blockIdx.x * 64 + (tid >> 3), p = tid & 7;
  const float* ps = pS + (size_t)ch * 256 + p * 32;
  const float* pq = pQ + (size_t)ch * 256 + p * 32;
  float s = 0.f, q = 0.f;
  #pragma unroll
  for (int i = 0; i < 32; ++i) { s += ps[i]; q += pq[i]; }
  #pragma unroll
  for (int off = 1; off < 8; off <<= 1) { s += __shfl_xor(s, off); q += __shfl_xor(q, off); }
  if (p == 0) {
    float mean = s * (1.0f / 16384.0f);
    float var  = q * (1.0f / 16384.0f) - mean * mean;
    mu[ch] = mean;
    inv[ch] = 1.0f / sqrtf(var + 1e-5f);
  }
}

// ---------------------------------------------------------------------------
// K4: BN normalize + final LIF scan, in-place on d_out, 16-deep load prefetch
// ---------------------------------------------------------------------------
__global__ __launch_bounds__(256) void final_kernel(
    float* __restrict__ y, const float* __restrict__ mu, const float* __restrict__ inv,
    const float* __restrict__ gamma, const float* __restrict__ beta) {
  int g = blockIdx.x * 256 + threadIdx.x;   // (b, m)
  int b = g >> 9, m = g & 511;
  float MU = mu[m], IV = inv[m], G = gamma[m], BE = beta[m];
  float* p = y + (size_t)b * NN + m;
  const size_t st = (size_t)BB * NN;
  float buf[16], nxt[16];
  #pragma unroll
  for (int j = 0; j < 16; ++j) buf[j] = p[(size_t)j * st];
  float v = 0.f;
  #pragma unroll
  for (int t0 = 0; t0 < 64; t0 += 16) {
    if (t0 + 16 < 64) {
      #pragma unroll
      for (int j = 0; j < 16; ++j) nxt[j] = p[(size_t)(t0 + 16 + j) * st];
    }
    #pragma unroll
    for (int j = 0; j < 16; ++j) {
      float xb = (buf[j] - MU) * IV * G + BE;
      v = v - v * 0.5f + xb;
      float s = (v >= 1.0f) ? 1.0f : 0.0f;
      p[(size_t)(t0 + j) * st] = s;
      if (s != 0.f) v = 0.f;
    }
    #pragma unroll
    for (int j = 0; j < 16; ++j) buf[j] = nxt[j];
  }
}

// ---------------------------------------------------------------------------
extern "C" void kernel_launch(void* const* d_in, const int* in_sizes, int n_in,
                              void* d_out, int out_size, void* d_ws, size_t ws_size,
                              hipStream_t stream) {
  const float* x     = (const float*)d_in[0];   // [T,B,N]
  const float* W     = (const float*)d_in[1];   // [N,N]
  const float* gamma = (const float*)d_in[2];   // [N]
  const float* beta  = (const float*)d_in[3];   // [N]
  float* out = (float*)d_out;                   // [T,B,N] fp32

  // workspace layout (~10.5 MB)
  char* ws = (char*)d_ws;
  signed char* wd       = (signed char*)ws;                 // 1,048,576
  unsigned char* spikes = (unsigned char*)(ws + 1048576);   // 8,388,608
  float* pS    = (float*)(ws + 9437184);                    //   524,288
  float* pQ    = (float*)(ws + 9961472);                    //   524,288
  float* bn_mu = (float*)(ws + 10485760);                   //     2,048
  float* bn_inv= (float*)(ws + 10487808);                   //     2,048

  wprep_kernel<<<dim3(1024), dim3(256), 0, stream>>>(W, wd);
  frontend_kernel<<<dim3(BB), dim3(512), 131072, stream>>>(x, spikes);
  gemm_kernel<<<dim3(128, 8), dim3(256), 0, stream>>>(spikes, wd, out, pS, pQ);
  bnstatsB_kernel<<<dim3(8), dim3(512), 0, stream>>>(pS, pQ, bn_mu, bn_inv);
  final_kernel<<<dim3(512), dim3(256), 0, stream>>>(out, bn_mu, bn_inv, gamma, beta);
}

// Round 5
// 146.646 us; speedup vs baseline: 1.7611x; 1.0402x over previous
//
#include <hip/hip_runtime.h>
#include <hip/hip_bf16.h>
#include <math.h>

// Problem constants (T=64, B=256, N=512)
#define TT 64
#define BB 256
#define NN 512

typedef int i32x4  __attribute__((ext_vector_type(4)));
typedef int i32x16 __attribute__((ext_vector_type(16)));

// global -> LDS direct DMA, 16B per lane. LDS dest must be wave-uniform base
// (HW adds lane*16); global src is per-lane.
__device__ __forceinline__ void gload16(const void* g, void* l) {
  __builtin_amdgcn_global_load_lds(
      (const __attribute__((address_space(1))) unsigned int*)g,
      (__attribute__((address_space(3))) unsigned int*)l, 16, 0, 0);
}

// ---------------------------------------------------------------------------
// K0: W -> 4 signed-i8 digit planes of round(W * 2^30). Exact reconstruction:
// W_int = d0 + (d1<<8) + (d2<<16) + (d3<<24); |W|<=0.0766 -> fits 27 bits.
// ---------------------------------------------------------------------------
__global__ __launch_bounds__(256) void wprep_kernel(
    const float* __restrict__ W, signed char* __restrict__ wd) {
  int i = blockIdx.x * 256 + threadIdx.x;
  float v = W[i];
  int q = __float2int_rn(v * 1073741824.0f);
  int d0 = ((q + 128) & 255) - 128; q = (q - d0) >> 8;
  int d1 = ((q + 128) & 255) - 128; q = (q - d1) >> 8;
  int d2 = ((q + 128) & 255) - 128; q = (q - d2) >> 8;
  wd[i]          = (signed char)d0;
  wd[262144 + i] = (signed char)d1;
  wd[524288 + i] = (signed char)d2;
  wd[786432 + i] = (signed char)q;   // |q| <= 9
}

// ---------------------------------------------------------------------------
// K1: fused front-end. One block per b. Stage x[:,b,:] (128KB) into LDS once,
// row-means -> spatial LIF (register/shfl chain, no LDS round-trips),
// col-means -> temporal gate, main gated LIF scan -> u8 spikes.
// ---------------------------------------------------------------------------
__global__ __launch_bounds__(512) void frontend_kernel(
    const float* __restrict__ x, unsigned char* __restrict__ spk) {
  extern __shared__ float xs[];          // [64][512] = 128 KB
  __shared__ float rms[TT];
  __shared__ float sp[TT];
  int b = blockIdx.x, tid = threadIdx.x;
  int l = tid & 63, w = tid >> 6;        // 8 waves
  #pragma unroll
  for (int p = 0; p < 16; ++p) {
    int f = p * 512 + tid;
    int t = f >> 7, c4 = f & 127;        // row t, float4 col c4
    gload16(x + (size_t)t * (BB * NN) + (size_t)b * NN + c4 * 4,
            (char*)xs + p * 8192 + w * 1024);
  }
  __syncthreads();                       // drains vmcnt(0) before barrier
  #pragma unroll
  for (int j = 0; j < 8; ++j) {          // wave w owns rows w*8..w*8+7
    int t = w * 8 + j;
    float s = 0.f;
    #pragma unroll
    for (int q = 0; q < 8; ++q) s += xs[t * 512 + q * 64 + l];
    #pragma unroll
    for (int off = 32; off; off >>= 1) s += __shfl_xor(s, off);
    if (l == 0) rms[t] = s;
  }
  float cs = 0.f;
  for (int t = 0; t < TT; ++t) cs += xs[t * 512 + tid];
  __syncthreads();
  // spatial LIF scan: wave 0, register chain via shfl broadcast (all lanes
  // compute the identical mask; ~12cy/step vs ~130cy LDS round-trip).
  if (w == 0) {
    float myrm = rms[l];
    float v = 0.f;
    unsigned long long mask = 0ull;
    #pragma unroll
    for (int t = 0; t < TT; ++t) {
      float m = __shfl(myrm, t) * (1.0f / 512.0f);
      v = v * 0.5f + m;                  // == v - v/2 + m exactly (v/2 exact)
      if (v >= 1.0f) { mask |= (1ull << t); v = 0.f; }
    }
    sp[l] = (float)((mask >> l) & 1ull);
  }
  __syncthreads();
  float te = (cs * (1.0f / 64.0f) >= 1.0f) ? 1.0f : 0.0f;
  float v = 0.f;
  unsigned char* sb = spk + (size_t)b * NN + tid;
  for (int t = 0; t < TT; ++t) {
    float xv = xs[t * 512 + tid];
    float a = xv + (xv * sp[t]) * (xv * te);  // ==xv exactly when a gate is 0
    v = v * 0.5f + a;
    unsigned char s = (v >= 1.0f) ? 1 : 0;
    sb[(size_t)t * (BB * NN)] = s;
    if (s) v = 0.f;
  }
}

// ---------------------------------------------------------------------------
// K2: i8 MFMA GEMM, 3-buffer counted-vmcnt pipeline (T3-min + T4 + T5).
// Block: 4 waves (2x2) -> 128 rows x 64 cols; BK=64.
// Schedule per iter t (cur=t%3):  lgkmcnt(0); vmcnt(6); s_barrier;
//   issue STAGE(t+2) into buf[(t+2)%3]; ds_read buf[cur]; setprio(1); 16 MFMA.
// vmcnt(6) leaves the newest stage (t+1) in flight ACROSS the barrier —
// each stage has ~2 iterations of latency cover (vs 0 with __syncthreads).
// Write-safety: STAGE(t+2) overwrites buf consumed at iter t-1; lgkmcnt(0)
// before the barrier guarantees all waves' reads of it completed.
// ---------------------------------------------------------------------------
__global__ __launch_bounds__(256) void gemm_kernel(
    const unsigned char* __restrict__ A, const signed char* __restrict__ Wd,
    float* __restrict__ C, float* __restrict__ pS, float* __restrict__ pQ) {
  __shared__ unsigned char sm[3][24576];
  int tid = threadIdx.x;
  int l = tid & 63, w = tid >> 6;
  int wr = w >> 1, wc = w & 1;
  int bx = blockIdx.x, by = blockIdx.y;
  int row0 = bx * 128, col0 = by * 64;
  int lr = l & 31, lh = l >> 5;

  i32x16 acc[2][4];
  #pragma unroll
  for (int f = 0; f < 2; ++f)
    #pragma unroll
    for (int d = 0; d < 4; ++d)
      #pragma unroll
      for (int j = 0; j < 16; ++j) acc[f][d][j] = 0;

  auto STAGE = [&](unsigned char* lbase, int kk) {
    #pragma unroll
    for (int j = 0; j < 2; ++j) {        // A chunks: c = wr_*4 + ff*2 + ss
      int c = j * 4 + w;
      int wr_ = c >> 2, ff = (c >> 1) & 1, ss = c & 1;
      gload16(A + (size_t)(row0 + wr_ * 64 + ff * 32 + lr) * NN + kk + ss * 32 + lh * 16,
              lbase + j * 4096 + w * 1024);
    }
    #pragma unroll
    for (int j = 0; j < 4; ++j) {        // B chunks: c = wc_*8 + dd*2 + ss
      int c = j * 4 + w;
      int wc_ = c >> 3, dd = (c >> 1) & 3, ss = c & 1;
      gload16(Wd + (size_t)dd * (NN * NN) + (size_t)(col0 + wc_ * 32 + lr) * NN + kk + ss * 32 + lh * 16,
              lbase + 8192 + j * 4096 + w * 1024);
    }
  };

  STAGE(sm[0], 0);     // S0
  STAGE(sm[1], 64);    // S1   (12 vm-ops outstanding per wave)
  #pragma unroll
  for (int t = 0; t < 8; ++t) {
    asm volatile("s_waitcnt lgkmcnt(0)" ::: "memory");   // my prior LDS reads done
    if (t < 7) asm volatile("s_waitcnt vmcnt(6)" ::: "memory");  // S_t landed, S_{t+1} in flight
    else       asm volatile("s_waitcnt vmcnt(0)" ::: "memory");
    asm volatile("s_barrier" ::: "memory");              // publish: buf[t%3] full, buf[(t+2)%3] free
    if (t < 6) STAGE(sm[(t + 2) % 3], (t + 2) * 64);
    const unsigned char* bp = sm[t % 3];
    i32x4 a[2][2], bfr[4][2];
    #pragma unroll
    for (int f = 0; f < 2; ++f)
      #pragma unroll
      for (int s = 0; s < 2; ++s)
        a[f][s] = *(const i32x4*)(bp + ((wr * 2 + f) * 2 + s) * 1024 + l * 16);
    #pragma unroll
    for (int d = 0; d < 4; ++d)
      #pragma unroll
      for (int s = 0; s < 2; ++s)
        bfr[d][s] = *(const i32x4*)(bp + 8192 + ((wc * 4 + d) * 2 + s) * 1024 + l * 16);
    __builtin_amdgcn_s_setprio(1);
    #pragma unroll
    for (int s = 0; s < 2; ++s)
      #pragma unroll
      for (int f = 0; f < 2; ++f)
        #pragma unroll
        for (int d = 0; d < 4; ++d)
          acc[f][d] = __builtin_amdgcn_mfma_i32_32x32x32_i8(a[f][s], bfr[d][s], acc[f][d], 0, 0, 0);
    __builtin_amdgcn_s_setprio(0);
  }

  // epilogue: exact digit combine, C write, BN partials.
  // lanes lh=0/1 share a column, different rows -> combine across lane^32.
  int col = col0 + wc * 32 + lr;
  float sy = 0.f, sq = 0.f;
  #pragma unroll
  for (int f = 0; f < 2; ++f) {
    #pragma unroll
    for (int j = 0; j < 16; ++j) {
      int t2 = acc[f][2][j] + (acc[f][3][j] << 8);
      int t1 = acc[f][1][j] + (t2 << 8);
      long long tt = ((long long)t1 << 8) + (long long)acc[f][0][j];
      float y = (float)tt * 0x1p-30f;
      int row = row0 + wr * 64 + f * 32 + (j & 3) + 8 * (j >> 2) + 4 * lh;
      C[(size_t)row * NN + col] = y;
      sy += y; sq += y * y;
    }
  }
  sy += __shfl_xor(sy, 32);
  sq += __shfl_xor(sq, 32);
  if (lh == 0) {
    pS[(size_t)col * 256 + bx * 2 + wr] = sy;
    pQ[(size_t)col * 256 + bx * 2 + wr] = sq;
  }
}

// ---------------------------------------------------------------------------
// K3: reduce 256 BN partials per channel -> mu, inv-std
// ---------------------------------------------------------------------------
__global__ __launch_bounds__(512) void bnstatsB_kernel(
    const float* __restrict__ pS, const float* __restrict__ pQ,
    float* __restrict__ mu, float* __restrict__ inv) {
  int tid = threadIdx.x;
  int ch = blockIdx.x * 64 + (tid >> 3), p = tid & 7;
  const float* ps = pS + (size_t)ch * 256 + p * 32;
  const float* pq = pQ + (size_t)ch * 256 + p * 32;
  float s = 0.f, q = 0.f;
  #pragma unroll
  for (int i = 0; i < 32; ++i) { s += ps[i]; q += pq[i]; }
  #pragma unroll
  for (int off = 1; off < 8; off <<= 1) { s += __shfl_xor(s, off); q += __shfl_xor(q, off); }
  if (p == 0) {
    float mean = s * (1.0f / 16384.0f);
    float var  = q * (1.0f / 16384.0f) - mean * mean;
    mu[ch] = mean;
    inv[ch] = 1.0f / sqrtf(var + 1e-5f);
  }
}

// ---------------------------------------------------------------------------
// K4: BN normalize + final LIF scan, in-place on d_out, 16-deep load prefetch
// ---------------------------------------------------------------------------
__global__ __launch_bounds__(256) void final_kernel(
    float* __restrict__ y, const float* __restrict__ mu, const float* __restrict__ inv,
    const float* __restrict__ gamma, const float* __restrict__ beta) {
  int g = blockIdx.x * 256 + threadIdx.x;   // (b, m)
  int b = g >> 9, m = g & 511;
  float MU = mu[m], IV = inv[m], G = gamma[m], BE = beta[m];
  float* p = y + (size_t)b * NN + m;
  const size_t st = (size_t)BB * NN;
  float buf[16], nxt[16];
  #pragma unroll
  for (int j = 0; j < 16; ++j) buf[j] = p[(size_t)j * st];
  float v = 0.f;
  #pragma unroll
  for (int t0 = 0; t0 < 64; t0 += 16) {
    if (t0 + 16 < 64) {
      #pragma unroll
      for (int j = 0; j < 16; ++j) nxt[j] = p[(size_t)(t0 + 16 + j) * st];
    }
    #pragma unroll
    for (int j = 0; j < 16; ++j) {
      float xb = (buf[j] - MU) * IV * G + BE;
      v = v * 0.5f + xb;
      float s = (v >= 1.0f) ? 1.0f : 0.0f;
      p[(size_t)(t0 + j) * st] = s;
      if (s != 0.f) v = 0.f;
    }
    #pragma unroll
    for (int j = 0; j < 16; ++j) buf[j] = nxt[j];
  }
}

// ---------------------------------------------------------------------------
extern "C" void kernel_launch(void* const* d_in, const int* in_sizes, int n_in,
                              void* d_out, int out_size, void* d_ws, size_t ws_size,
                              hipStream_t stream) {
  const float* x     = (const float*)d_in[0];   // [T,B,N]
  const float* W     = (const float*)d_in[1];   // [N,N]
  const float* gamma = (const float*)d_in[2];   // [N]
  const float* beta  = (const float*)d_in[3];   // [N]
  float* out = (float*)d_out;                   // [T,B,N] fp32

  // workspace layout (~10.5 MB)
  char* ws = (char*)d_ws;
  signed char* wd       = (signed char*)ws;                 // 1,048,576
  unsigned char* spikes = (unsigned char*)(ws + 1048576);   // 8,388,608
  float* pS    = (float*)(ws + 9437184);                    //   524,288
  float* pQ    = (float*)(ws + 9961472);                    //   524,288
  float* bn_mu = (float*)(ws + 10485760);                   //     2,048
  float* bn_inv= (float*)(ws + 10487808);                   //     2,048

  wprep_kernel<<<dim3(1024), dim3(256), 0, stream>>>(W, wd);
  frontend_kernel<<<dim3(BB), dim3(512), 131072, stream>>>(x, spikes);
  gemm_kernel<<<dim3(128, 8), dim3(256), 0, stream>>>(spikes, wd, out, pS, pQ);
  bnstatsB_kernel<<<dim3(8), dim3(512), 0, stream>>>(pS, pQ, bn_mu, bn_inv);
  final_kernel<<<dim3(512), dim3(256), 0, stream>>>(out, bn_mu, bn_inv, gamma, beta);
}